// Round 15
// baseline (286.070 us; speedup 1.0000x reference)
//
#include <hip/hip_runtime.h>
#include <hip/hip_bf16.h>
#include <math.h>

// SGConv: x = emb[x_indices]; 3 hops of D^-1/2 (A+I) D^-1/2; out = x3 @ W^T + b.
// z-space: z = dinv*x; hop: z' = dinv^2*(z[c] + sum_{r->c} z[r]); last hop dinv^1.
// LEDGER (verified r0-13): emb/w/b fp32, out fp32, ei contiguous (2,E),
// index widths runtime-classified, bf16 z validated (absmax 4.9e-4).
// r14 (fixed compile in r15): (1) degree-sorted hop slots (wave = 8
// degree-matched nodes; kills E[max8 Poisson16]=23.5 vs 16 divergence),
// (2) staging packed to 4B/edge (r | clocal<<23), (3) hop unroll x8.

#define FLAG_MX 0
#define FLAG_ME 1
#define SH 9        // 512 cols per bucket
#define WC 512      // cols per bucket
#define CH 4096     // edges per P1/P3 block
#define RMASK 0x7FFFFFu

using short8 = __attribute__((ext_vector_type(8))) short;
using f32x4 = __attribute__((ext_vector_type(4))) float;

__device__ inline int idx_at(const void* p, long long i, int mode) {
    switch (mode) {
        case 1: return (int)((const long long*)p)[i];
        case 2: return (int)((const float*)p)[i];
        case 3: return (int)((const double*)p)[i];
        default: return ((const int*)p)[i];
    }
}

// bf16 helpers (RNE pack, shift unpack)
__device__ inline unsigned short f2bf(float f) {
    union { float f; unsigned u; } v; v.f = f;
    unsigned r = v.u + 0x7FFFu + ((v.u >> 16) & 1u);
    return (unsigned short)(r >> 16);
}
__device__ inline float bflo(unsigned d) { union { unsigned u; float f; } v; v.u = d << 16; return v.f; }
__device__ inline float bfhi(unsigned d) { union { unsigned u; float f; } v; v.u = d & 0xFFFF0000u; return v.f; }
__device__ inline unsigned pk(float a, float b) {
    return (unsigned)f2bf(a) | ((unsigned)f2bf(b) << 16);
}

__device__ int detect_me_block(const void* ei, int n, int* sbuf) {
    int t = threadIdx.x;
    int oke = 15;
    const int* w = (const int*)ei;
    const long long* L = (const long long*)ei;
    const float* f = (const float*)ei;
    const double* d = (const double*)ei;
    for (int k = t; k < 2048; k += 256) {
        if (!((unsigned)w[k] < (unsigned)n)) oke &= ~1;
        long long lv = L[k];
        if (!(lv >= 0 && lv < (long long)n)) oke &= ~2;
        float fv = f[k];
        if (!(fv >= 0.f && fv < (float)n && fv == truncf(fv))) oke &= ~4;
        double dv = d[k];
        if (!(dv >= 0.0 && dv < (double)n && dv == trunc(dv))) oke &= ~8;
    }
    sbuf[t] = oke;
    __syncthreads();
    for (int st = 128; st; st >>= 1) {
        if (t < st) sbuf[t] &= sbuf[t + st];
        __syncthreads();
    }
    int r = sbuf[0];
    __syncthreads();
    return (r & 2) ? 1 : (r & 8) ? 3 : (r & 4) ? 2 : 0;
}

__device__ int detect_mx_block(const void* xidx, int* sbuf) {
    int t = threadIdx.x;
    int okx = 15;
    const int* w = (const int*)xidx;
    const long long* L = (const long long*)xidx;
    const float* f = (const float*)xidx;
    const double* d = (const double*)xidx;
    for (int k = t; k < 2048; k += 256) {
        if (w[k] != k) okx &= ~1;
        if (L[k] != (long long)k) okx &= ~2;
        if (!(f[k] == (float)k)) okx &= ~4;
        if (!(d[k] == (double)k)) okx &= ~8;
    }
    sbuf[t] = okx;
    __syncthreads();
    for (int st = 128; st; st >>= 1) {
        if (t < st) sbuf[t] &= sbuf[t + st];
        __syncthreads();
    }
    int r = sbuf[0];
    __syncthreads();
    return (r & 2) ? 1 : (r & 8) ? 3 : (r & 4) ? 2 : 0;
}

// P1: inline classify (block 0 publishes flags) + per-block bucket histogram.
__global__ void __launch_bounds__(256) k_p1(
        const void* __restrict__ ei, const void* __restrict__ xidx,
        long long E, int n, int NBUK, int NBLK,
        int* __restrict__ bhist, int* __restrict__ flags) {
    __shared__ int hist[256];
    __shared__ int sbuf[256];
    int t = threadIdx.x;
    int blk = blockIdx.x;
    int me = detect_me_block(ei, n, sbuf);
    if (blk == 0) {
        int mx = detect_mx_block(xidx, sbuf);
        if (t == 0) { flags[FLAG_ME] = me; flags[FLAG_MX] = mx; }
    }
    long long base = (long long)blk * CH;
    int cnt = (int)min((long long)CH, E - base);
    hist[t] = 0;
    __syncthreads();
    for (int i = t; i < cnt; i += 256) {
        int c = idx_at(ei, E + base + i, me);
        int b = min(c >> SH, NBUK - 1);
        atomicAdd(&hist[b], 1);
    }
    __syncthreads();
    if (t < NBUK) bhist[(size_t)t * NBLK + blk] = hist[t];
}

// P2a: per-bucket chunked LDS exclusive scan over block-counts (in place).
__global__ void __launch_bounds__(256) k_p2a(
        int* __restrict__ bhist, int* __restrict__ gcount, int NBLK) {
    __shared__ int s[256];
    int b = blockIdx.x;
    int t = threadIdx.x;
    int* row = bhist + (size_t)b * NBLK;
    int carry = 0;
    for (int base = 0; base < NBLK; base += 256) {
        int i = base + t;
        int v = (i < NBLK) ? row[i] : 0;
        s[t] = v;
        __syncthreads();
        for (int st = 1; st < 256; st <<= 1) {
            int add = (t >= st) ? s[t - st] : 0;
            __syncthreads();
            s[t] += add;
            __syncthreads();
        }
        if (i < NBLK) row[i] = carry + s[t] - v;  // exclusive
        int total = s[255];
        __syncthreads();
        carry += total;
    }
    if (t == 0) gcount[b] = carry;
}

// P2b: exclusive scan over bucket totals -> gbase[NBUK+1].
__global__ void k_p2b(const int* gcount, int* gbase, int NBUK) {
    __shared__ int s[256];
    int t = threadIdx.x;
    int v = (t < NBUK) ? gcount[t] : 0;
    s[t] = v;
    __syncthreads();
    for (int st = 1; st < 256; st <<= 1) {
        int add = (t >= st) ? s[t - st] : 0;
        __syncthreads();
        s[t] += add;
        __syncthreads();
    }
    if (t < NBUK) gbase[t] = s[t] - v;
    if (t == NBUK - 1) gbase[NBUK] = s[t];
}

// P3: block-local counting sort by bucket; write packed (r | clocal<<23)
// to bucket-major staging (4B/edge). Zero global atomics.
__global__ void __launch_bounds__(256) k_p3(
        const void* __restrict__ ei, long long E, int n, int NBUK, int NBLK,
        const int* __restrict__ bhist, const int* __restrict__ gbase,
        unsigned* __restrict__ gstag, const int* __restrict__ flags) {
    __shared__ int hist[256], lbase[256], rsv[256], lcur[256], s[256];
    __shared__ unsigned stage[CH];
    int t = threadIdx.x;
    int blk = blockIdx.x;
    long long base = (long long)blk * CH;
    int cnt = (int)min((long long)CH, E - base);
    int me = flags[FLAG_ME];
    hist[t] = 0;
    __syncthreads();
    for (int i = t; i < cnt; i += 256) {
        int c = idx_at(ei, E + base + i, me);
        atomicAdd(&hist[min(c >> SH, NBUK - 1)], 1);
    }
    __syncthreads();
    int v = hist[t];
    s[t] = v;
    __syncthreads();
    for (int st = 1; st < 256; st <<= 1) {
        int add = (t >= st) ? s[t - st] : 0;
        __syncthreads();
        s[t] += add;
        __syncthreads();
    }
    lbase[t] = s[t] - v;
    lcur[t] = s[t] - v;
    if (t < NBUK) rsv[t] = gbase[t] + bhist[(size_t)t * NBLK + blk];
    __syncthreads();
    for (int i = t; i < cnt; i += 256) {
        long long e = base + i;
        int r = idx_at(ei, e, me);
        int c = idx_at(ei, E + e, me);
        int b = min(c >> SH, NBUK - 1);
        unsigned pkv = ((unsigned)r & RMASK) |
                       (((unsigned)(c - (b << SH)) & (WC - 1)) << 23);
        int slot = atomicAdd(&lcur[b], 1);
        stage[slot] = pkv;
    }
    __syncthreads();
    // slot i belongs to bucket b where lbase[b] <= i < lbase[b]+hist[b]:
    // binary search over the sorted lbase array.
    for (int i = t; i < cnt; i += 256) {
        unsigned pkv = stage[i];
        int lo = 0, hi = NBUK - 1;
        while (lo < hi) {
            int mid = (lo + hi + 1) >> 1;
            if (lbase[mid] <= i) lo = mid; else hi = mid - 1;
        }
        gstag[rsv[lo] + (i - lbase[lo])] = pkv;
    }
}

// P4: one block per bucket: col histogram + scan; dinv; rowidx placement;
// degree-sorted slot arrays (nodep/offp/degp) for degree-uniform hop waves.
__global__ void __launch_bounds__(256) k_p4(
        const unsigned* __restrict__ gstag, const int* __restrict__ gbase,
        float* __restrict__ dinv, int* __restrict__ rowidx,
        int* __restrict__ nodep, int* __restrict__ offp, int* __restrict__ degp,
        int n) {
    __shared__ int hist[WC], lofs[WC], cur[WC], p[256];
    __shared__ int dcnt[64], dbase[64];
    int t = threadIdx.x;
    int b = blockIdx.x;
    int cbase = b << SH;
    int e0 = gbase[b], e1 = gbase[b + 1];
    int cnt = e1 - e0;
    hist[t] = 0; hist[t + 256] = 0;
    if (t < 64) dcnt[t] = 0;
    __syncthreads();
    for (int i = t; i < cnt; i += 256) {
        int cl = (int)(gstag[e0 + i] >> 23);
        atomicAdd(&hist[cl], 1);
    }
    __syncthreads();
    int a0 = hist[2 * t], a1 = hist[2 * t + 1];
    int s2 = a0 + a1;
    p[t] = s2;
    __syncthreads();
    for (int st = 1; st < 256; st <<= 1) {
        int add = (t >= st) ? p[t - st] : 0;
        __syncthreads();
        p[t] += add;
        __syncthreads();
    }
    int excl = p[t] - s2;
    lofs[2 * t] = excl;       cur[2 * t] = excl;
    lofs[2 * t + 1] = excl + a0; cur[2 * t + 1] = excl + a0;
    __syncthreads();
    int ncols = n - cbase;
    if (ncols < 0) ncols = 0;
    if (ncols > WC) ncols = WC;
    for (int j = t; j < ncols; j += 256) {
        dinv[cbase + j] = rsqrtf((float)(hist[j] + 1));  // +1 self-loop
        atomicAdd(&dcnt[min(hist[j], 63)], 1);
    }
    for (int j = ncols + t; j < WC; j += 256) {
        int s = b * WC + j;
        nodep[s] = -1; degp[s] = 0; offp[s] = 0;
    }
    __syncthreads();
    if (t == 0) {
        int run = 0;
        for (int d = 0; d < 64; d++) { dbase[d] = run; run += dcnt[d]; }
    }
    __syncthreads();
    for (int j = t; j < ncols; j += 256) {
        int d = min(hist[j], 63);
        int r = atomicAdd(&dbase[d], 1);
        int s = b * WC + r;
        nodep[s] = cbase + j;
        offp[s] = e0 + lofs[j];
        degp[s] = hist[j];
    }
    for (int i = t; i < cnt; i += 256) {
        unsigned pkv = gstag[e0 + i];
        int cl = (int)(pkv >> 23);
        int slot = atomicAdd(&cur[cl], 1);
        rowidx[e0 + slot] = (int)(pkv & RMASK);
    }
}

// z0: z[node] = emb[xidx[node]] * dinv[node], bf16 out; thread = 16B chunk.
__global__ void __launch_bounds__(256) k_z0(
        const void* __restrict__ xidx, const float4* __restrict__ emb4,
        const float* __restrict__ dinv, uint4* __restrict__ z, int n,
        const int* __restrict__ flags) {
    int i = blockIdx.x * 256 + threadIdx.x;
    if (i >= n * 8) return;
    int node = i >> 3, q = i & 7;
    int xi = idx_at(xidx, node, flags[FLAG_MX]);
    if ((unsigned)xi >= (unsigned)n) xi = 0;
    float d = dinv[node];
    float4 a = emb4[(long long)xi * 16 + q * 2];
    float4 b = emb4[(long long)xi * 16 + q * 2 + 1];
    uint4 o;
    o.x = pk(a.x * d, a.y * d);
    o.y = pk(a.z * d, a.w * d);
    o.z = pk(b.x * d, b.y * d);
    o.w = pk(b.z * d, b.w * d);
    z[(long long)node * 8 + q] = o;
}

__device__ inline void acc8(float* acc, uint4 s) {
    acc[0] += bflo(s.x); acc[1] += bfhi(s.x);
    acc[2] += bflo(s.y); acc[3] += bfhi(s.y);
    acc[4] += bflo(s.z); acc[5] += bfhi(s.z);
    acc[6] += bflo(s.w); acc[7] += bfhi(s.w);
}

// hop over degree-sorted slots: wave = 8 degree-matched nodes, lane = 16B chunk.
__global__ void __launch_bounds__(256) k_hop(
        const uint4* __restrict__ zin, uint4* __restrict__ zout,
        const float* __restrict__ dinv, const int* __restrict__ rowidx,
        const int* __restrict__ nodep, const int* __restrict__ offp,
        const int* __restrict__ degp, int n, int nslots, int last) {
    int tid = blockIdx.x * 256 + threadIdx.x;
    int slot = tid >> 3;
    int q = tid & 7;
    if (slot >= nslots) return;
    int node = nodep[slot];
    if ((unsigned)node >= (unsigned)n) return;
    float acc[8];
    {
        uint4 s = zin[(long long)node * 8 + q];  // self-loop
        acc[0] = bflo(s.x); acc[1] = bfhi(s.x);
        acc[2] = bflo(s.y); acc[3] = bfhi(s.y);
        acc[4] = bflo(s.z); acc[5] = bfhi(s.z);
        acc[6] = bflo(s.w); acc[7] = bfhi(s.w);
    }
    int e = offp[slot];
    int e1 = e + degp[slot];
    for (; e + 8 <= e1; e += 8) {
        int r0 = rowidx[e + 0], r1 = rowidx[e + 1];
        int r2 = rowidx[e + 2], r3 = rowidx[e + 3];
        int r4 = rowidx[e + 4], r5 = rowidx[e + 5];
        int r6 = rowidx[e + 6], r7 = rowidx[e + 7];
        uint4 s0 = zin[(long long)r0 * 8 + q];
        uint4 s1 = zin[(long long)r1 * 8 + q];
        uint4 s2 = zin[(long long)r2 * 8 + q];
        uint4 s3 = zin[(long long)r3 * 8 + q];
        uint4 s4 = zin[(long long)r4 * 8 + q];
        uint4 s5 = zin[(long long)r5 * 8 + q];
        uint4 s6 = zin[(long long)r6 * 8 + q];
        uint4 s7 = zin[(long long)r7 * 8 + q];
        acc8(acc, s0); acc8(acc, s1); acc8(acc, s2); acc8(acc, s3);
        acc8(acc, s4); acc8(acc, s5); acc8(acc, s6); acc8(acc, s7);
    }
    for (; e + 2 <= e1; e += 2) {
        int r0 = rowidx[e], r1 = rowidx[e + 1];
        uint4 s0 = zin[(long long)r0 * 8 + q];
        uint4 s1 = zin[(long long)r1 * 8 + q];
        acc8(acc, s0); acc8(acc, s1);
    }
    for (; e < e1; e++) acc8(acc, zin[(long long)rowidx[e] * 8 + q]);
    float d = dinv[node];
    float sc = last ? d : d * d;
    uint4 o;
    o.x = pk(acc[0] * sc, acc[1] * sc);
    o.y = pk(acc[2] * sc, acc[3] * sc);
    o.z = pk(acc[4] * sc, acc[5] * sc);
    o.w = pk(acc[6] * sc, acc[7] * sc);
    zout[(long long)node * 8 + q] = o;
}

// MFMA linear: out[m][o] = sum_k x3[m][k]*W[o][k] + b[o].
__global__ void __launch_bounds__(256) k_lin_mfma(
        const short8* __restrict__ x8, const float* __restrict__ w,
        const float* __restrict__ b, float* __restrict__ out, int n, int ntiles) {
    int lane = threadIdx.x & 63;
    int wv = threadIdx.x >> 6;
    int col = lane & 15, quad = lane >> 4;

    short8 bw[4][2];
#pragma unroll
    for (int tN = 0; tN < 4; tN++)
#pragma unroll
        for (int s = 0; s < 2; s++) {
            const float* src = w + (tN * 16 + col) * 64 + s * 32 + quad * 8;
            short8 v;
#pragma unroll
            for (int j = 0; j < 8; j++) v[j] = (short)f2bf(src[j]);
            bw[tN][s] = v;
        }
    float bv[4];
#pragma unroll
    for (int tN = 0; tN < 4; tN++) bv[tN] = b[tN * 16 + col];

    int tile = blockIdx.x * 4 + wv;
    if (tile >= ntiles) return;
    int node0 = tile * 16;

    short8 a[2];
    int m = node0 + col;
#pragma unroll
    for (int s = 0; s < 2; s++) {
        if (m < n) a[s] = x8[(size_t)m * 8 + s * 4 + quad];
        else a[s] = short8{0, 0, 0, 0, 0, 0, 0, 0};
    }
#pragma unroll
    for (int tN = 0; tN < 4; tN++) {
        f32x4 acc = {bv[tN], bv[tN], bv[tN], bv[tN]};
        acc = __builtin_amdgcn_mfma_f32_16x16x32_bf16(a[0], bw[tN][0], acc, 0, 0, 0);
        acc = __builtin_amdgcn_mfma_f32_16x16x32_bf16(a[1], bw[tN][1], acc, 0, 0, 0);
#pragma unroll
        for (int r = 0; r < 4; r++) {
            int node = node0 + quad * 4 + r;
            if (node < n) out[(size_t)node * 64 + tN * 16 + col] = acc[r];
        }
    }
}

extern "C" void kernel_launch(void* const* d_in, const int* in_sizes, int n_in,
                              void* d_out, int out_size, void* d_ws, size_t ws_size,
                              hipStream_t stream) {
    const void* xidx = d_in[0];
    const void* ei = d_in[1];
    const float* emb = (const float*)d_in[2];
    const float* w = (const float*)d_in[3];
    const float* b = (const float*)d_in[4];

    const int n = in_sizes[0];
    const long long E = in_sizes[1] / 2;
    int NBUK = (int)((n + WC - 1) >> SH);
    if (NBUK > 256) NBUK = 256;  // dataset: n=100k -> 196
    const int NBLK = (int)((E + CH - 1) / CH);
    const int nslots = NBUK * WC;

    char* p = (char*)d_ws;
    auto alloc = [&](size_t bytes) -> void* {
        void* r = (void*)p;
        p += (bytes + 255) & ~(size_t)255;
        return r;
    };
    int* flags = (int*)alloc(256);
    float* dinv = (float*)alloc((size_t)n * 4);
    int* gcount = (int*)alloc(257 * 4);
    int* gbase = (int*)alloc(258 * 4);
    int* bhist = (int*)alloc((size_t)NBLK * NBUK * 4);
    int* rowidx = (int*)alloc((size_t)E * 4);
    int* nodep = (int*)alloc((size_t)nslots * 4);
    int* offp = (int*)alloc((size_t)nslots * 4);
    int* degp = (int*)alloc((size_t)nslots * 4);
    uint4* zA = (uint4*)alloc((size_t)n * 64 * 2);  // bf16 z (12.8 MB)
    uint4* zS = (uint4*)d_out;                      // bf16 z in d_out 1st half

    // packed staging (4B/edge) in d_out's 2nd half (E*4 <= n*64*2 here)
    unsigned* gstag;
    if ((size_t)E * 4 <= (size_t)n * 64 * 2)
        gstag = (unsigned*)((char*)d_out + (size_t)n * 64 * 2);
    else
        gstag = (unsigned*)alloc((size_t)E * 4);

    k_p1<<<NBLK, 256, 0, stream>>>(ei, xidx, E, n, NBUK, NBLK, bhist, flags);
    k_p2a<<<NBUK, 256, 0, stream>>>(bhist, gcount, NBLK);
    k_p2b<<<1, 256, 0, stream>>>(gcount, gbase, NBUK);
    k_p3<<<NBLK, 256, 0, stream>>>(ei, E, n, NBUK, NBLK, bhist, gbase, gstag, flags);
    k_p4<<<NBUK, 256, 0, stream>>>(gstag, gbase, dinv, rowidx, nodep, offp, degp, n);

    const int gZ = (n * 8 + 255) / 256;
    const int gH = (nslots * 8 + 255) / 256;
    const int ntiles = (n + 15) / 16;
    const int gM = (ntiles + 3) / 4;

    k_z0<<<gZ, 256, 0, stream>>>(xidx, (const float4*)emb, dinv, zS, n, flags);
    k_hop<<<gH, 256, 0, stream>>>(zS, zA, dinv, rowidx, nodep, offp, degp, n, nslots, 0);
    k_hop<<<gH, 256, 0, stream>>>(zA, zS, dinv, rowidx, nodep, offp, degp, n, nslots, 0);
    k_hop<<<gH, 256, 0, stream>>>(zS, zA, dinv, rowidx, nodep, offp, degp, n, nslots, 1);
    k_lin_mfma<<<gM, 256, 0, stream>>>((const short8*)zA, w, b, (float*)d_out,
                                       n, ntiles);
}

// Round 16
// 282.683 us; speedup vs baseline: 1.0120x; 1.0120x over previous
//
#include <hip/hip_runtime.h>
#include <hip/hip_bf16.h>
#include <math.h>

// SGConv: x = emb[x_indices]; 3 hops of D^-1/2 (A+I) D^-1/2; out = x3 @ W^T + b.
// z-space: z = dinv*x; hop: z' = dinv^2*(z[c] + sum_{r->c} z[r]); last hop dinv^1.
// LEDGER (verified r0-15): emb/w/b fp32, out fp32, ei contiguous (2,E),
// index widths runtime-classified, bf16 z validated (absmax 4.9e-4).
// r15->r16: REVERT degree-sorted hop (r14/15 regressed 264.6->286.1: scattered
// self-loop reads + zout writes cost more than divergence saved). Keep 4B
// packed staging. Fold p2b into p3/p4 (in-block gcount scan); fuse z0 into p4.

#define FLAG_MX 0
#define FLAG_ME 1
#define SH 9        // 512 cols per bucket
#define WC 512      // cols per bucket
#define CH 4096     // edges per P1/P3 block
#define RMASK 0x7FFFFFu

using short8 = __attribute__((ext_vector_type(8))) short;
using f32x4 = __attribute__((ext_vector_type(4))) float;

__device__ inline int idx_at(const void* p, long long i, int mode) {
    switch (mode) {
        case 1: return (int)((const long long*)p)[i];
        case 2: return (int)((const float*)p)[i];
        case 3: return (int)((const double*)p)[i];
        default: return ((const int*)p)[i];
    }
}

// bf16 helpers (RNE pack, shift unpack)
__device__ inline unsigned short f2bf(float f) {
    union { float f; unsigned u; } v; v.f = f;
    unsigned r = v.u + 0x7FFFu + ((v.u >> 16) & 1u);
    return (unsigned short)(r >> 16);
}
__device__ inline float bflo(unsigned d) { union { unsigned u; float f; } v; v.u = d << 16; return v.f; }
__device__ inline float bfhi(unsigned d) { union { unsigned u; float f; } v; v.u = d & 0xFFFF0000u; return v.f; }
__device__ inline unsigned pk(float a, float b) {
    return (unsigned)f2bf(a) | ((unsigned)f2bf(b) << 16);
}

__device__ int detect_me_block(const void* ei, int n, int* sbuf) {
    int t = threadIdx.x;
    int oke = 15;
    const int* w = (const int*)ei;
    const long long* L = (const long long*)ei;
    const float* f = (const float*)ei;
    const double* d = (const double*)ei;
    for (int k = t; k < 2048; k += 256) {
        if (!((unsigned)w[k] < (unsigned)n)) oke &= ~1;
        long long lv = L[k];
        if (!(lv >= 0 && lv < (long long)n)) oke &= ~2;
        float fv = f[k];
        if (!(fv >= 0.f && fv < (float)n && fv == truncf(fv))) oke &= ~4;
        double dv = d[k];
        if (!(dv >= 0.0 && dv < (double)n && dv == trunc(dv))) oke &= ~8;
    }
    sbuf[t] = oke;
    __syncthreads();
    for (int st = 128; st; st >>= 1) {
        if (t < st) sbuf[t] &= sbuf[t + st];
        __syncthreads();
    }
    int r = sbuf[0];
    __syncthreads();
    return (r & 2) ? 1 : (r & 8) ? 3 : (r & 4) ? 2 : 0;
}

__device__ int detect_mx_block(const void* xidx, int* sbuf) {
    int t = threadIdx.x;
    int okx = 15;
    const int* w = (const int*)xidx;
    const long long* L = (const long long*)xidx;
    const float* f = (const float*)xidx;
    const double* d = (const double*)xidx;
    for (int k = t; k < 2048; k += 256) {
        if (w[k] != k) okx &= ~1;
        if (L[k] != (long long)k) okx &= ~2;
        if (!(f[k] == (float)k)) okx &= ~4;
        if (!(d[k] == (double)k)) okx &= ~8;
    }
    sbuf[t] = okx;
    __syncthreads();
    for (int st = 128; st; st >>= 1) {
        if (t < st) sbuf[t] &= sbuf[t + st];
        __syncthreads();
    }
    int r = sbuf[0];
    __syncthreads();
    return (r & 2) ? 1 : (r & 8) ? 3 : (r & 4) ? 2 : 0;
}

// P1: inline classify (block 0 publishes flags) + per-block bucket histogram
// -> bhist[b*NBLK + blk] (bucket-major).
__global__ void __launch_bounds__(256) k_p1(
        const void* __restrict__ ei, const void* __restrict__ xidx,
        long long E, int n, int NBUK, int NBLK,
        int* __restrict__ bhist, int* __restrict__ flags) {
    __shared__ int hist[256];
    __shared__ int sbuf[256];
    int t = threadIdx.x;
    int blk = blockIdx.x;
    int me = detect_me_block(ei, n, sbuf);
    if (blk == 0) {
        int mx = detect_mx_block(xidx, sbuf);
        if (t == 0) { flags[FLAG_ME] = me; flags[FLAG_MX] = mx; }
    }
    long long base = (long long)blk * CH;
    int cnt = (int)min((long long)CH, E - base);
    hist[t] = 0;
    __syncthreads();
    for (int i = t; i < cnt; i += 256) {
        int c = idx_at(ei, E + base + i, me);
        int b = min(c >> SH, NBUK - 1);
        atomicAdd(&hist[b], 1);
    }
    __syncthreads();
    if (t < NBUK) bhist[(size_t)t * NBLK + blk] = hist[t];
}

// P2a: per-bucket chunked LDS exclusive scan over block-counts (in place);
// gcount[b] = bucket total.
__global__ void __launch_bounds__(256) k_p2a(
        int* __restrict__ bhist, int* __restrict__ gcount, int NBLK) {
    __shared__ int s[256];
    int b = blockIdx.x;
    int t = threadIdx.x;
    int* row = bhist + (size_t)b * NBLK;
    int carry = 0;
    for (int base = 0; base < NBLK; base += 256) {
        int i = base + t;
        int v = (i < NBLK) ? row[i] : 0;
        s[t] = v;
        __syncthreads();
        for (int st = 1; st < 256; st <<= 1) {
            int add = (t >= st) ? s[t - st] : 0;
            __syncthreads();
            s[t] += add;
            __syncthreads();
        }
        if (i < NBLK) row[i] = carry + s[t] - v;  // exclusive
        int total = s[255];
        __syncthreads();
        carry += total;
    }
    if (t == 0) gcount[b] = carry;
}

// in-block exclusive scan of gcount (NBUK <= 256) -> gb_ex[]; returns total.
__device__ void scan_gcount(const int* gcount, int NBUK, int* p, int* gb_ex) {
    int t = threadIdx.x;
    int v = (t < NBUK) ? gcount[t] : 0;
    p[t] = v;
    __syncthreads();
    for (int st = 1; st < 256; st <<= 1) {
        int add = (t >= st) ? p[t - st] : 0;
        __syncthreads();
        p[t] += add;
        __syncthreads();
    }
    gb_ex[t] = p[t] - v;  // exclusive prefix
    __syncthreads();
}

// P3: block-local counting sort by bucket; write packed (r | clocal<<23)
// to bucket-major staging (4B/edge). Zero global atomics.
__global__ void __launch_bounds__(256) k_p3(
        const void* __restrict__ ei, long long E, int n, int NBUK, int NBLK,
        const int* __restrict__ bhist, const int* __restrict__ gcount,
        unsigned* __restrict__ gstag, const int* __restrict__ flags) {
    __shared__ int hist[256], lbase[256], rsv[256], lcur[256], s[256], gb[256];
    __shared__ unsigned stage[CH];
    int t = threadIdx.x;
    int blk = blockIdx.x;
    scan_gcount(gcount, NBUK, s, gb);
    long long base = (long long)blk * CH;
    int cnt = (int)min((long long)CH, E - base);
    int me = flags[FLAG_ME];
    hist[t] = 0;
    __syncthreads();
    for (int i = t; i < cnt; i += 256) {
        int c = idx_at(ei, E + base + i, me);
        atomicAdd(&hist[min(c >> SH, NBUK - 1)], 1);
    }
    __syncthreads();
    int v = hist[t];
    s[t] = v;
    __syncthreads();
    for (int st = 1; st < 256; st <<= 1) {
        int add = (t >= st) ? s[t - st] : 0;
        __syncthreads();
        s[t] += add;
        __syncthreads();
    }
    lbase[t] = s[t] - v;
    lcur[t] = s[t] - v;
    if (t < NBUK) rsv[t] = gb[t] + bhist[(size_t)t * NBLK + blk];
    __syncthreads();
    for (int i = t; i < cnt; i += 256) {
        long long e = base + i;
        int r = idx_at(ei, e, me);
        int c = idx_at(ei, E + e, me);
        int b = min(c >> SH, NBUK - 1);
        unsigned pkv = ((unsigned)r & RMASK) |
                       (((unsigned)(c - (b << SH)) & (WC - 1)) << 23);
        int slot = atomicAdd(&lcur[b], 1);
        stage[slot] = pkv;
    }
    __syncthreads();
    // slot i belongs to bucket b where lbase[b] <= i < lbase[b]+hist[b]
    for (int i = t; i < cnt; i += 256) {
        unsigned pkv = stage[i];
        int lo = 0, hi = NBUK - 1;
        while (lo < hi) {
            int mid = (lo + hi + 1) >> 1;
            if (lbase[mid] <= i) lo = mid; else hi = mid - 1;
        }
        gstag[rsv[lo] + (i - lbase[lo])] = pkv;
    }
}

// P4: one block per bucket: col histogram + scan -> off/dinv; rowidx
// placement; FUSED z0 for the bucket's own nodes (z = dinv*emb[xidx], bf16).
__global__ void __launch_bounds__(256) k_p4(
        const unsigned* __restrict__ gstag, const int* __restrict__ gcount,
        int* __restrict__ off, float* __restrict__ dinv,
        int* __restrict__ rowidx, const void* __restrict__ xidx,
        const float4* __restrict__ emb4, uint4* __restrict__ zS,
        const int* __restrict__ flags, int n, int NBUK, long long E) {
    __shared__ int hist[WC], lofs[WC], cur[WC], p[256], gb[256];
    int t = threadIdx.x;
    int b = blockIdx.x;
    int cbase = b << SH;
    scan_gcount(gcount, NBUK, p, gb);
    int e0 = gb[b];
    int e1 = e0 + gcount[b];
    int cnt = e1 - e0;
    if (b == NBUK - 1 && t == 0) off[n] = e1;  // == E
    hist[t] = 0; hist[t + 256] = 0;
    __syncthreads();
    for (int i = t; i < cnt; i += 256) {
        int cl = (int)(gstag[e0 + i] >> 23);
        atomicAdd(&hist[cl], 1);
    }
    __syncthreads();
    int a0 = hist[2 * t], a1 = hist[2 * t + 1];
    int s2 = a0 + a1;
    p[t] = s2;
    __syncthreads();
    for (int st = 1; st < 256; st <<= 1) {
        int add = (t >= st) ? p[t - st] : 0;
        __syncthreads();
        p[t] += add;
        __syncthreads();
    }
    int excl = p[t] - s2;
    lofs[2 * t] = excl;       cur[2 * t] = excl;
    lofs[2 * t + 1] = excl + a0; cur[2 * t + 1] = excl + a0;
    __syncthreads();
    int ncols = n - cbase;
    if (ncols < 0) ncols = 0;
    if (ncols > WC) ncols = WC;
    for (int j = t; j < ncols; j += 256) {
        off[cbase + j] = e0 + lofs[j];
        dinv[cbase + j] = rsqrtf((float)(hist[j] + 1));  // +1 self-loop
    }
    // rowidx placement into the bucket's contiguous slice
    for (int i = t; i < cnt; i += 256) {
        unsigned pkv = gstag[e0 + i];
        int cl = (int)(pkv >> 23);
        int slot = atomicAdd(&cur[cl], 1);
        rowidx[e0 + slot] = (int)(pkv & RMASK);
    }
    // fused z0 for this bucket's nodes: z[node] = dinv[node] * emb[xidx[node]]
    int mx = flags[FLAG_MX];
    for (int i = t; i < ncols * 8; i += 256) {
        int j = i >> 3, q = i & 7;
        int node = cbase + j;
        int xi = idx_at(xidx, node, mx);
        if ((unsigned)xi >= (unsigned)n) xi = 0;
        float dv = rsqrtf((float)(hist[j] + 1));
        float4 a = emb4[(long long)xi * 16 + q * 2];
        float4 bb = emb4[(long long)xi * 16 + q * 2 + 1];
        uint4 o;
        o.x = pk(a.x * dv, a.y * dv);
        o.y = pk(a.z * dv, a.w * dv);
        o.z = pk(bb.x * dv, bb.y * dv);
        o.w = pk(bb.z * dv, bb.w * dv);
        zS[(long long)node * 8 + q] = o;
    }
}

__device__ inline void acc8(float* acc, uint4 s) {
    acc[0] += bflo(s.x); acc[1] += bfhi(s.x);
    acc[2] += bflo(s.y); acc[3] += bfhi(s.y);
    acc[4] += bflo(s.z); acc[5] += bfhi(s.z);
    acc[6] += bflo(s.w); acc[7] += bfhi(s.w);
}

// hop: 8 contiguous nodes per wave; lane = one 16B chunk (8 bf16).
// Inner loop unrolled x4 (r13-proven structure).
__global__ void __launch_bounds__(256) k_hop(
        const uint4* __restrict__ zin, uint4* __restrict__ zout,
        const float* __restrict__ dinv, const int* __restrict__ off,
        const int* __restrict__ rowidx, int n, int last) {
    int tid = blockIdx.x * 256 + threadIdx.x;
    int node = tid >> 3;
    int q = tid & 7;
    if (node >= n) return;
    float acc[8];
    {
        uint4 s = zin[(long long)node * 8 + q];  // self-loop
        acc[0] = bflo(s.x); acc[1] = bfhi(s.x);
        acc[2] = bflo(s.y); acc[3] = bfhi(s.y);
        acc[4] = bflo(s.z); acc[5] = bfhi(s.z);
        acc[6] = bflo(s.w); acc[7] = bfhi(s.w);
    }
    int e0 = off[node], e1 = off[node + 1];
    int e = e0;
    for (; e + 4 <= e1; e += 4) {
        int r0 = rowidx[e + 0];
        int r1 = rowidx[e + 1];
        int r2 = rowidx[e + 2];
        int r3 = rowidx[e + 3];
        uint4 s0 = zin[(long long)r0 * 8 + q];
        uint4 s1 = zin[(long long)r1 * 8 + q];
        uint4 s2 = zin[(long long)r2 * 8 + q];
        uint4 s3 = zin[(long long)r3 * 8 + q];
        acc8(acc, s0);
        acc8(acc, s1);
        acc8(acc, s2);
        acc8(acc, s3);
    }
    for (; e < e1; e++) {
        int r = rowidx[e];
        acc8(acc, zin[(long long)r * 8 + q]);
    }
    float d = dinv[node];
    float sc = last ? d : d * d;
    uint4 o;
    o.x = pk(acc[0] * sc, acc[1] * sc);
    o.y = pk(acc[2] * sc, acc[3] * sc);
    o.z = pk(acc[4] * sc, acc[5] * sc);
    o.w = pk(acc[6] * sc, acc[7] * sc);
    zout[(long long)node * 8 + q] = o;
}

// MFMA linear: out[m][o] = sum_k x3[m][k]*W[o][k] + b[o].
__global__ void __launch_bounds__(256) k_lin_mfma(
        const short8* __restrict__ x8, const float* __restrict__ w,
        const float* __restrict__ b, float* __restrict__ out, int n, int ntiles) {
    int lane = threadIdx.x & 63;
    int wv = threadIdx.x >> 6;
    int col = lane & 15, quad = lane >> 4;

    short8 bw[4][2];
#pragma unroll
    for (int tN = 0; tN < 4; tN++)
#pragma unroll
        for (int s = 0; s < 2; s++) {
            const float* src = w + (tN * 16 + col) * 64 + s * 32 + quad * 8;
            short8 v;
#pragma unroll
            for (int j = 0; j < 8; j++) v[j] = (short)f2bf(src[j]);
            bw[tN][s] = v;
        }
    float bv[4];
#pragma unroll
    for (int tN = 0; tN < 4; tN++) bv[tN] = b[tN * 16 + col];

    int tile = blockIdx.x * 4 + wv;
    if (tile >= ntiles) return;
    int node0 = tile * 16;

    short8 a[2];
    int m = node0 + col;
#pragma unroll
    for (int s = 0; s < 2; s++) {
        if (m < n) a[s] = x8[(size_t)m * 8 + s * 4 + quad];
        else a[s] = short8{0, 0, 0, 0, 0, 0, 0, 0};
    }
#pragma unroll
    for (int tN = 0; tN < 4; tN++) {
        f32x4 acc = {bv[tN], bv[tN], bv[tN], bv[tN]};
        acc = __builtin_amdgcn_mfma_f32_16x16x32_bf16(a[0], bw[tN][0], acc, 0, 0, 0);
        acc = __builtin_amdgcn_mfma_f32_16x16x32_bf16(a[1], bw[tN][1], acc, 0, 0, 0);
#pragma unroll
        for (int r = 0; r < 4; r++) {
            int node = node0 + quad * 4 + r;
            if (node < n) out[(size_t)node * 64 + tN * 16 + col] = acc[r];
        }
    }
}

extern "C" void kernel_launch(void* const* d_in, const int* in_sizes, int n_in,
                              void* d_out, int out_size, void* d_ws, size_t ws_size,
                              hipStream_t stream) {
    const void* xidx = d_in[0];
    const void* ei = d_in[1];
    const float* emb = (const float*)d_in[2];
    const float* w = (const float*)d_in[3];
    const float* b = (const float*)d_in[4];

    const int n = in_sizes[0];
    const long long E = in_sizes[1] / 2;
    int NBUK = (int)((n + WC - 1) >> SH);
    if (NBUK > 256) NBUK = 256;  // dataset: n=100k -> 196
    const int NBLK = (int)((E + CH - 1) / CH);

    char* p = (char*)d_ws;
    auto alloc = [&](size_t bytes) -> void* {
        void* r = (void*)p;
        p += (bytes + 255) & ~(size_t)255;
        return r;
    };
    int* flags = (int*)alloc(256);
    float* dinv = (float*)alloc((size_t)n * 4);
    int* off = (int*)alloc((size_t)(n + 1) * 4);
    int* gcount = (int*)alloc(257 * 4);
    int* bhist = (int*)alloc((size_t)NBLK * NBUK * 4);
    int* rowidx = (int*)alloc((size_t)E * 4);
    uint4* zA = (uint4*)alloc((size_t)n * 64 * 2);  // bf16 z (12.8 MB)
    uint4* zS = (uint4*)d_out;                      // bf16 z in d_out 1st half

    // packed staging (4B/edge) in d_out's 2nd half (E*4 <= n*64*2 here)
    unsigned* gstag;
    if ((size_t)E * 4 <= (size_t)n * 64 * 2)
        gstag = (unsigned*)((char*)d_out + (size_t)n * 64 * 2);
    else
        gstag = (unsigned*)alloc((size_t)E * 4);

    k_p1<<<NBLK, 256, 0, stream>>>(ei, xidx, E, n, NBUK, NBLK, bhist, flags);
    k_p2a<<<NBUK, 256, 0, stream>>>(bhist, gcount, NBLK);
    k_p3<<<NBLK, 256, 0, stream>>>(ei, E, n, NBUK, NBLK, bhist, gcount, gstag, flags);
    k_p4<<<NBUK, 256, 0, stream>>>(gstag, gcount, off, dinv, rowidx, xidx,
                                   (const float4*)emb, zS, flags, n, NBUK, E);

    const int gF = (n * 8 + 255) / 256;
    const int ntiles = (n + 15) / 16;
    const int gM = (ntiles + 3) / 4;

    // hops zS->zA->zS->zA; mfma-linear zA -> d_out.
    k_hop<<<gF, 256, 0, stream>>>(zS, zA, dinv, off, rowidx, n, 0);
    k_hop<<<gF, 256, 0, stream>>>(zA, zS, dinv, off, rowidx, n, 0);
    k_hop<<<gF, 256, 0, stream>>>(zS, zA, dinv, off, rowidx, n, 1);
    k_lin_mfma<<<gM, 256, 0, stream>>>((const short8*)zA, w, b, (float*)d_out,
                                       n, ntiles);
}

// Round 17
// 259.173 us; speedup vs baseline: 1.1038x; 1.0907x over previous
//
#include <hip/hip_runtime.h>
#include <hip/hip_bf16.h>
#include <math.h>

// SGConv: x = emb[x_indices]; 3 hops of D^-1/2 (A+I) D^-1/2; out = x3 @ W^T + b.
// z-space: z = dinv*x; hop: z' = dinv^2*(z[c] + sum_{r->c} z[r]); last hop dinv^1.
// LEDGER (verified r0-16): emb/w/b fp32, out fp32, ei contiguous (2,E),
// index widths runtime-classified, bf16 z validated (absmax 4.9e-4).
// r16->r17: UN-FUSE z0 from p4 (r16 regression: 800k random gathers inside a
// 196-block kernel = parallelism-starved, 47us). p4 now 512 threads/block.
// Keep: 4B packed staging, folded p2b, contiguous unroll-4 hop (r13-proven).

#define FLAG_MX 0
#define FLAG_ME 1
#define SH 9        // 512 cols per bucket
#define WC 512      // cols per bucket
#define CH 4096     // edges per P1/P3 block
#define RMASK 0x7FFFFFu

using short8 = __attribute__((ext_vector_type(8))) short;
using f32x4 = __attribute__((ext_vector_type(4))) float;

__device__ inline int idx_at(const void* p, long long i, int mode) {
    switch (mode) {
        case 1: return (int)((const long long*)p)[i];
        case 2: return (int)((const float*)p)[i];
        case 3: return (int)((const double*)p)[i];
        default: return ((const int*)p)[i];
    }
}

// bf16 helpers (RNE pack, shift unpack)
__device__ inline unsigned short f2bf(float f) {
    union { float f; unsigned u; } v; v.f = f;
    unsigned r = v.u + 0x7FFFu + ((v.u >> 16) & 1u);
    return (unsigned short)(r >> 16);
}
__device__ inline float bflo(unsigned d) { union { unsigned u; float f; } v; v.u = d << 16; return v.f; }
__device__ inline float bfhi(unsigned d) { union { unsigned u; float f; } v; v.u = d & 0xFFFF0000u; return v.f; }
__device__ inline unsigned pk(float a, float b) {
    return (unsigned)f2bf(a) | ((unsigned)f2bf(b) << 16);
}

__device__ int detect_me_block(const void* ei, int n, int* sbuf) {
    int t = threadIdx.x;
    int oke = 15;
    const int* w = (const int*)ei;
    const long long* L = (const long long*)ei;
    const float* f = (const float*)ei;
    const double* d = (const double*)ei;
    for (int k = t; k < 2048; k += 256) {
        if (!((unsigned)w[k] < (unsigned)n)) oke &= ~1;
        long long lv = L[k];
        if (!(lv >= 0 && lv < (long long)n)) oke &= ~2;
        float fv = f[k];
        if (!(fv >= 0.f && fv < (float)n && fv == truncf(fv))) oke &= ~4;
        double dv = d[k];
        if (!(dv >= 0.0 && dv < (double)n && dv == trunc(dv))) oke &= ~8;
    }
    sbuf[t] = oke;
    __syncthreads();
    for (int st = 128; st; st >>= 1) {
        if (t < st) sbuf[t] &= sbuf[t + st];
        __syncthreads();
    }
    int r = sbuf[0];
    __syncthreads();
    return (r & 2) ? 1 : (r & 8) ? 3 : (r & 4) ? 2 : 0;
}

__device__ int detect_mx_block(const void* xidx, int* sbuf) {
    int t = threadIdx.x;
    int okx = 15;
    const int* w = (const int*)xidx;
    const long long* L = (const long long*)xidx;
    const float* f = (const float*)xidx;
    const double* d = (const double*)xidx;
    for (int k = t; k < 2048; k += 256) {
        if (w[k] != k) okx &= ~1;
        if (L[k] != (long long)k) okx &= ~2;
        if (!(f[k] == (float)k)) okx &= ~4;
        if (!(d[k] == (double)k)) okx &= ~8;
    }
    sbuf[t] = okx;
    __syncthreads();
    for (int st = 128; st; st >>= 1) {
        if (t < st) sbuf[t] &= sbuf[t + st];
        __syncthreads();
    }
    int r = sbuf[0];
    __syncthreads();
    return (r & 2) ? 1 : (r & 8) ? 3 : (r & 4) ? 2 : 0;
}

// P1: inline classify (block 0 publishes flags) + per-block bucket histogram
// -> bhist[b*NBLK + blk] (bucket-major).
__global__ void __launch_bounds__(256) k_p1(
        const void* __restrict__ ei, const void* __restrict__ xidx,
        long long E, int n, int NBUK, int NBLK,
        int* __restrict__ bhist, int* __restrict__ flags) {
    __shared__ int hist[256];
    __shared__ int sbuf[256];
    int t = threadIdx.x;
    int blk = blockIdx.x;
    int me = detect_me_block(ei, n, sbuf);
    if (blk == 0) {
        int mx = detect_mx_block(xidx, sbuf);
        if (t == 0) { flags[FLAG_ME] = me; flags[FLAG_MX] = mx; }
    }
    long long base = (long long)blk * CH;
    int cnt = (int)min((long long)CH, E - base);
    hist[t] = 0;
    __syncthreads();
    for (int i = t; i < cnt; i += 256) {
        int c = idx_at(ei, E + base + i, me);
        int b = min(c >> SH, NBUK - 1);
        atomicAdd(&hist[b], 1);
    }
    __syncthreads();
    if (t < NBUK) bhist[(size_t)t * NBLK + blk] = hist[t];
}

// P2a: per-bucket chunked LDS exclusive scan over block-counts (in place);
// gcount[b] = bucket total.
__global__ void __launch_bounds__(256) k_p2a(
        int* __restrict__ bhist, int* __restrict__ gcount, int NBLK) {
    __shared__ int s[256];
    int b = blockIdx.x;
    int t = threadIdx.x;
    int* row = bhist + (size_t)b * NBLK;
    int carry = 0;
    for (int base = 0; base < NBLK; base += 256) {
        int i = base + t;
        int v = (i < NBLK) ? row[i] : 0;
        s[t] = v;
        __syncthreads();
        for (int st = 1; st < 256; st <<= 1) {
            int add = (t >= st) ? s[t - st] : 0;
            __syncthreads();
            s[t] += add;
            __syncthreads();
        }
        if (i < NBLK) row[i] = carry + s[t] - v;  // exclusive
        int total = s[255];
        __syncthreads();
        carry += total;
    }
    if (t == 0) gcount[b] = carry;
}

// in-block exclusive scan of gcount (NBUK <= 256), 256-thread version.
__device__ void scan_gcount(const int* gcount, int NBUK, int* p, int* gb_ex) {
    int t = threadIdx.x;
    int v = (t < NBUK) ? gcount[t] : 0;
    p[t] = v;
    __syncthreads();
    for (int st = 1; st < 256; st <<= 1) {
        int add = (t >= st) ? p[t - st] : 0;
        __syncthreads();
        p[t] += add;
        __syncthreads();
    }
    gb_ex[t] = p[t] - v;
    __syncthreads();
}

// 512-thread version (threads >= 256 ride along through the syncs).
__device__ void scan_gcount_512(const int* gcount, int NBUK, int* p, int* gb_ex) {
    int t = threadIdx.x;
    int v = (t < 256) ? ((t < NBUK) ? gcount[t] : 0) : 0;
    if (t < 256) p[t] = v;
    __syncthreads();
    for (int st = 1; st < 256; st <<= 1) {
        int add = (t >= st && t < 256) ? p[t - st] : 0;
        __syncthreads();
        if (t < 256) p[t] += add;
        __syncthreads();
    }
    if (t < 256) gb_ex[t] = p[t] - v;
    __syncthreads();
}

// P3: block-local counting sort by bucket; write packed (r | clocal<<23)
// to bucket-major staging (4B/edge). Zero global atomics.
__global__ void __launch_bounds__(256) k_p3(
        const void* __restrict__ ei, long long E, int n, int NBUK, int NBLK,
        const int* __restrict__ bhist, const int* __restrict__ gcount,
        unsigned* __restrict__ gstag, const int* __restrict__ flags) {
    __shared__ int hist[256], lbase[256], rsv[256], lcur[256], s[256], gb[256];
    __shared__ unsigned stage[CH];
    int t = threadIdx.x;
    int blk = blockIdx.x;
    scan_gcount(gcount, NBUK, s, gb);
    long long base = (long long)blk * CH;
    int cnt = (int)min((long long)CH, E - base);
    int me = flags[FLAG_ME];
    hist[t] = 0;
    __syncthreads();
    for (int i = t; i < cnt; i += 256) {
        int c = idx_at(ei, E + base + i, me);
        atomicAdd(&hist[min(c >> SH, NBUK - 1)], 1);
    }
    __syncthreads();
    int v = hist[t];
    s[t] = v;
    __syncthreads();
    for (int st = 1; st < 256; st <<= 1) {
        int add = (t >= st) ? s[t - st] : 0;
        __syncthreads();
        s[t] += add;
        __syncthreads();
    }
    lbase[t] = s[t] - v;
    lcur[t] = s[t] - v;
    if (t < NBUK) rsv[t] = gb[t] + bhist[(size_t)t * NBLK + blk];
    __syncthreads();
    for (int i = t; i < cnt; i += 256) {
        long long e = base + i;
        int r = idx_at(ei, e, me);
        int c = idx_at(ei, E + e, me);
        int b = min(c >> SH, NBUK - 1);
        unsigned pkv = ((unsigned)r & RMASK) |
                       (((unsigned)(c - (b << SH)) & (WC - 1)) << 23);
        int slot = atomicAdd(&lcur[b], 1);
        stage[slot] = pkv;
    }
    __syncthreads();
    // slot i belongs to bucket b where lbase[b] <= i < lbase[b]+hist[b]
    for (int i = t; i < cnt; i += 256) {
        unsigned pkv = stage[i];
        int lo = 0, hi = NBUK - 1;
        while (lo < hi) {
            int mid = (lo + hi + 1) >> 1;
            if (lbase[mid] <= i) lo = mid; else hi = mid - 1;
        }
        gstag[rsv[lo] + (i - lbase[lo])] = pkv;
    }
}

// P4 (512 threads): one block per bucket: col histogram + scan -> off/dinv;
// rowidx placement into the bucket's contiguous slice. No z0 here (r16 lesson).
__global__ void __launch_bounds__(512) k_p4(
        const unsigned* __restrict__ gstag, const int* __restrict__ gcount,
        int* __restrict__ off, float* __restrict__ dinv,
        int* __restrict__ rowidx, int n, int NBUK) {
    __shared__ int hist[WC], lofs[WC], cur[WC], p[512], gb[256];
    int t = threadIdx.x;  // 0..511
    int b = blockIdx.x;
    int cbase = b << SH;
    scan_gcount_512(gcount, NBUK, p, gb);
    int e0 = gb[b];
    int e1 = e0 + gcount[b];
    int cnt = e1 - e0;
    if (b == NBUK - 1 && t == 0) off[n] = e1;  // == E
    hist[t] = 0;
    __syncthreads();
    for (int i = t; i < cnt; i += 512) {
        atomicAdd(&hist[gstag[e0 + i] >> 23], 1);
    }
    __syncthreads();
    // 512-wide exclusive scan, 1 elem/thread
    int v = hist[t];
    p[t] = v;
    __syncthreads();
    for (int st = 1; st < 512; st <<= 1) {
        int add = (t >= st) ? p[t - st] : 0;
        __syncthreads();
        p[t] += add;
        __syncthreads();
    }
    int excl = p[t] - v;
    lofs[t] = excl;
    cur[t] = excl;
    __syncthreads();
    int ncols = n - cbase;
    if (ncols < 0) ncols = 0;
    if (ncols > WC) ncols = WC;
    if (t < ncols) {
        off[cbase + t] = e0 + lofs[t];
        dinv[cbase + t] = rsqrtf((float)(hist[t] + 1));  // +1 self-loop
    }
    for (int i = t; i < cnt; i += 512) {
        unsigned pkv = gstag[e0 + i];
        int cl = (int)(pkv >> 23);
        int slot = atomicAdd(&cur[cl], 1);
        rowidx[e0 + slot] = (int)(pkv & RMASK);
    }
}

// z0: z[node] = emb[xidx[node]] * dinv[node], bf16 out; thread = 16B chunk.
__global__ void __launch_bounds__(256) k_z0(
        const void* __restrict__ xidx, const float4* __restrict__ emb4,
        const float* __restrict__ dinv, uint4* __restrict__ z, int n,
        const int* __restrict__ flags) {
    int i = blockIdx.x * 256 + threadIdx.x;
    if (i >= n * 8) return;
    int node = i >> 3, q = i & 7;
    int xi = idx_at(xidx, node, flags[FLAG_MX]);
    if ((unsigned)xi >= (unsigned)n) xi = 0;
    float d = dinv[node];
    float4 a = emb4[(long long)xi * 16 + q * 2];
    float4 b = emb4[(long long)xi * 16 + q * 2 + 1];
    uint4 o;
    o.x = pk(a.x * d, a.y * d);
    o.y = pk(a.z * d, a.w * d);
    o.z = pk(b.x * d, b.y * d);
    o.w = pk(b.z * d, b.w * d);
    z[(long long)node * 8 + q] = o;
}

__device__ inline void acc8(float* acc, uint4 s) {
    acc[0] += bflo(s.x); acc[1] += bfhi(s.x);
    acc[2] += bflo(s.y); acc[3] += bfhi(s.y);
    acc[4] += bflo(s.z); acc[5] += bfhi(s.z);
    acc[6] += bflo(s.w); acc[7] += bfhi(s.w);
}

// hop: 8 contiguous nodes per wave; lane = one 16B chunk (8 bf16).
// Inner loop unrolled x4 (r13-proven structure).
__global__ void __launch_bounds__(256) k_hop(
        const uint4* __restrict__ zin, uint4* __restrict__ zout,
        const float* __restrict__ dinv, const int* __restrict__ off,
        const int* __restrict__ rowidx, int n, int last) {
    int tid = blockIdx.x * 256 + threadIdx.x;
    int node = tid >> 3;
    int q = tid & 7;
    if (node >= n) return;
    float acc[8];
    {
        uint4 s = zin[(long long)node * 8 + q];  // self-loop
        acc[0] = bflo(s.x); acc[1] = bfhi(s.x);
        acc[2] = bflo(s.y); acc[3] = bfhi(s.y);
        acc[4] = bflo(s.z); acc[5] = bfhi(s.z);
        acc[6] = bflo(s.w); acc[7] = bfhi(s.w);
    }
    int e0 = off[node], e1 = off[node + 1];
    int e = e0;
    for (; e + 4 <= e1; e += 4) {
        int r0 = rowidx[e + 0];
        int r1 = rowidx[e + 1];
        int r2 = rowidx[e + 2];
        int r3 = rowidx[e + 3];
        uint4 s0 = zin[(long long)r0 * 8 + q];
        uint4 s1 = zin[(long long)r1 * 8 + q];
        uint4 s2 = zin[(long long)r2 * 8 + q];
        uint4 s3 = zin[(long long)r3 * 8 + q];
        acc8(acc, s0);
        acc8(acc, s1);
        acc8(acc, s2);
        acc8(acc, s3);
    }
    for (; e < e1; e++) {
        int r = rowidx[e];
        acc8(acc, zin[(long long)r * 8 + q]);
    }
    float d = dinv[node];
    float sc = last ? d : d * d;
    uint4 o;
    o.x = pk(acc[0] * sc, acc[1] * sc);
    o.y = pk(acc[2] * sc, acc[3] * sc);
    o.z = pk(acc[4] * sc, acc[5] * sc);
    o.w = pk(acc[6] * sc, acc[7] * sc);
    zout[(long long)node * 8 + q] = o;
}

// MFMA linear: out[m][o] = sum_k x3[m][k]*W[o][k] + b[o].
__global__ void __launch_bounds__(256) k_lin_mfma(
        const short8* __restrict__ x8, const float* __restrict__ w,
        const float* __restrict__ b, float* __restrict__ out, int n, int ntiles) {
    int lane = threadIdx.x & 63;
    int wv = threadIdx.x >> 6;
    int col = lane & 15, quad = lane >> 4;

    short8 bw[4][2];
#pragma unroll
    for (int tN = 0; tN < 4; tN++)
#pragma unroll
        for (int s = 0; s < 2; s++) {
            const float* src = w + (tN * 16 + col) * 64 + s * 32 + quad * 8;
            short8 v;
#pragma unroll
            for (int j = 0; j < 8; j++) v[j] = (short)f2bf(src[j]);
            bw[tN][s] = v;
        }
    float bv[4];
#pragma unroll
    for (int tN = 0; tN < 4; tN++) bv[tN] = b[tN * 16 + col];

    int tile = blockIdx.x * 4 + wv;
    if (tile >= ntiles) return;
    int node0 = tile * 16;

    short8 a[2];
    int m = node0 + col;
#pragma unroll
    for (int s = 0; s < 2; s++) {
        if (m < n) a[s] = x8[(size_t)m * 8 + s * 4 + quad];
        else a[s] = short8{0, 0, 0, 0, 0, 0, 0, 0};
    }
#pragma unroll
    for (int tN = 0; tN < 4; tN++) {
        f32x4 acc = {bv[tN], bv[tN], bv[tN], bv[tN]};
        acc = __builtin_amdgcn_mfma_f32_16x16x32_bf16(a[0], bw[tN][0], acc, 0, 0, 0);
        acc = __builtin_amdgcn_mfma_f32_16x16x32_bf16(a[1], bw[tN][1], acc, 0, 0, 0);
#pragma unroll
        for (int r = 0; r < 4; r++) {
            int node = node0 + quad * 4 + r;
            if (node < n) out[(size_t)node * 64 + tN * 16 + col] = acc[r];
        }
    }
}

extern "C" void kernel_launch(void* const* d_in, const int* in_sizes, int n_in,
                              void* d_out, int out_size, void* d_ws, size_t ws_size,
                              hipStream_t stream) {
    const void* xidx = d_in[0];
    const void* ei = d_in[1];
    const float* emb = (const float*)d_in[2];
    const float* w = (const float*)d_in[3];
    const float* b = (const float*)d_in[4];

    const int n = in_sizes[0];
    const long long E = in_sizes[1] / 2;
    int NBUK = (int)((n + WC - 1) >> SH);
    if (NBUK > 256) NBUK = 256;  // dataset: n=100k -> 196
    const int NBLK = (int)((E + CH - 1) / CH);

    char* p = (char*)d_ws;
    auto alloc = [&](size_t bytes) -> void* {
        void* r = (void*)p;
        p += (bytes + 255) & ~(size_t)255;
        return r;
    };
    int* flags = (int*)alloc(256);
    float* dinv = (float*)alloc((size_t)n * 4);
    int* off = (int*)alloc((size_t)(n + 1) * 4);
    int* gcount = (int*)alloc(257 * 4);
    int* bhist = (int*)alloc((size_t)NBLK * NBUK * 4);
    int* rowidx = (int*)alloc((size_t)E * 4);
    uint4* zA = (uint4*)alloc((size_t)n * 64 * 2);  // bf16 z (12.8 MB)
    uint4* zS = (uint4*)d_out;                      // bf16 z in d_out 1st half

    // packed staging (4B/edge) in d_out's 2nd half (E*4 <= n*64*2 here)
    unsigned* gstag;
    if ((size_t)E * 4 <= (size_t)n * 64 * 2)
        gstag = (unsigned*)((char*)d_out + (size_t)n * 64 * 2);
    else
        gstag = (unsigned*)alloc((size_t)E * 4);

    k_p1<<<NBLK, 256, 0, stream>>>(ei, xidx, E, n, NBUK, NBLK, bhist, flags);
    k_p2a<<<NBUK, 256, 0, stream>>>(bhist, gcount, NBLK);
    k_p3<<<NBLK, 256, 0, stream>>>(ei, E, n, NBUK, NBLK, bhist, gcount, gstag, flags);
    k_p4<<<NBUK, 512, 0, stream>>>(gstag, gcount, off, dinv, rowidx, n, NBUK);

    const int gF = (n * 8 + 255) / 256;
    const int ntiles = (n + 15) / 16;
    const int gM = (ntiles + 3) / 4;

    // z0 -> zS(d_out 1st half); hops zS->zA->zS->zA; mfma-linear zA -> d_out.
    k_z0<<<gF, 256, 0, stream>>>(xidx, (const float4*)emb, dinv, zS, n, flags);
    k_hop<<<gF, 256, 0, stream>>>(zS, zA, dinv, off, rowidx, n, 0);
    k_hop<<<gF, 256, 0, stream>>>(zA, zS, dinv, off, rowidx, n, 0);
    k_hop<<<gF, 256, 0, stream>>>(zS, zA, dinv, off, rowidx, n, 1);
    k_lin_mfma<<<gM, 256, 0, stream>>>((const short8*)zA, w, b, (float*)d_out,
                                       n, ntiles);
}